// Round 1
// baseline (205.577 us; speedup 1.0000x reference)
//
#include <hip/hip_runtime.h>

#define BATCH 8
#define NPTS 16384
#define MSKEL 1000
#define NCLS 100
#define CKK 10
#define MINDIS_INITF 100000.0f

// ws layout (floats): [0 .. BATCH*MSKEL) = per-(b,m) min d^2 as uint bits
//                     [BATCH*MSKEL]      = n-side sum accumulator

__global__ __launch_bounds__(256) void k_init(unsigned int* minbits, float* sumN) {
    int i = blockIdx.x * 256 + threadIdx.x;
    if (i < BATCH * MSKEL) minbits[i] = 0x7F800000u;  // +inf
    if (i == 0) sumN[0] = 0.0f;
}

// n-side chamfer: one thread per point, skel in LDS, min over m of d^2
__global__ __launch_bounds__(256) void k_nside(const float* __restrict__ xyz,
                                               const float* __restrict__ skel,
                                               float* __restrict__ sumN) {
    __shared__ float4 s_skel[MSKEL];
    const int b = blockIdx.x >> 6;        // 64 tiles of 256 points per batch
    const int tile = blockIdx.x & 63;
    const float* sb = skel + (size_t)b * MSKEL * 3;
    for (int i = threadIdx.x; i < MSKEL; i += 256) {
        s_skel[i] = make_float4(sb[i * 3 + 0], sb[i * 3 + 1], sb[i * 3 + 2], 0.0f);
    }
    __syncthreads();

    const int n = tile * 256 + threadIdx.x;
    const float* p = xyz + ((size_t)b * NPTS + n) * 6;
    const float px = p[0], py = p[1], pz = p[2];

    float mind2 = 3.4e38f;
#pragma unroll 4
    for (int m = 0; m < MSKEL; ++m) {
        float4 s = s_skel[m];
        float dx = px - s.x, dy = py - s.y, dz = pz - s.z;
        float d2 = dx * dx + dy * dy + dz * dz;
        mind2 = fminf(mind2, d2);
    }
    float d = sqrtf(fmaxf(mind2, 1e-12f));

    // block reduce sum
#pragma unroll
    for (int o = 32; o > 0; o >>= 1) d += __shfl_down(d, o, 64);
    __shared__ float s_part[4];
    const int wave = threadIdx.x >> 6, lane = threadIdx.x & 63;
    if (lane == 0) s_part[wave] = d;
    __syncthreads();
    if (threadIdx.x == 0) {
        atomicAdd(sumN, s_part[0] + s_part[1] + s_part[2] + s_part[3]);
    }
}

// m-side chamfer: tile of points in LDS, 4 skel points per thread in registers
#define TILE_N 512
__global__ __launch_bounds__(256) void k_mside(const float* __restrict__ xyz,
                                               const float* __restrict__ skel,
                                               unsigned int* __restrict__ minbits) {
    __shared__ float4 s_pts[TILE_N];
    const int b = blockIdx.x >> 5;        // 32 tiles of 512 points per batch
    const int tile = blockIdx.x & 31;
    const float* xb = xyz + ((size_t)b * NPTS + tile * TILE_N) * 6;
    for (int i = threadIdx.x; i < TILE_N; i += 256) {
        s_pts[i] = make_float4(xb[i * 6 + 0], xb[i * 6 + 1], xb[i * 6 + 2], 0.0f);
    }
    __syncthreads();

    float sx[4], sy[4], sz[4], mind[4];
    int mi[4];
#pragma unroll
    for (int k = 0; k < 4; ++k) {
        int m = threadIdx.x + k * 256;
        mi[k] = m;
        if (m < MSKEL) {
            const float* s = skel + ((size_t)b * MSKEL + m) * 3;
            sx[k] = s[0]; sy[k] = s[1]; sz[k] = s[2];
        } else {
            sx[k] = 0.0f; sy[k] = 0.0f; sz[k] = 0.0f;
        }
        mind[k] = 3.4e38f;
    }

#pragma unroll 2
    for (int n = 0; n < TILE_N; ++n) {
        float4 p = s_pts[n];  // broadcast read: all lanes same address
#pragma unroll
        for (int k = 0; k < 4; ++k) {
            float dx = p.x - sx[k], dy = p.y - sy[k], dz = p.z - sz[k];
            float d2 = dx * dx + dy * dy + dz * dz;
            mind[k] = fminf(mind[k], d2);
        }
    }
#pragma unroll
    for (int k = 0; k < 4; ++k) {
        if (mi[k] < MSKEL) {
            // d2 >= 0, so uint bit ordering == float ordering
            atomicMin(&minbits[b * MSKEL + mi[k]], __float_as_uint(mind[k]));
        }
    }
}

// finalize: sum m-side mins, convex-hull term, combine
__global__ __launch_bounds__(256) void k_final(const float* __restrict__ skel,
                                               const int* __restrict__ labels,
                                               const unsigned int* __restrict__ minbits,
                                               const float* __restrict__ sumN,
                                               float* __restrict__ out) {
    const int tid = threadIdx.x;
    float skelSum = 0.0f;
    for (int i = tid; i < BATCH * MSKEL; i += 256) {
        float d2 = __uint_as_float(minbits[i]);
        skelSum += sqrtf(fmaxf(d2, 1e-12f));
    }

    float convexSum = 0.0f;
    for (int task = tid; task < BATCH * NCLS; task += 256) {
        const int b = task / NCLS, c = task % NCLS;
        const float* cp = skel + ((size_t)b * MSKEL + c * CKK) * 3;
        const int* lab = labels + (size_t)b * NCLS * CKK + c * CKK;
        float x[CKK], y[CKK], z[CKK];
        int lv[CKK];
#pragma unroll
        for (int i = 0; i < CKK; ++i) {
            x[i] = cp[i * 3 + 0]; y[i] = cp[i * 3 + 1]; z[i] = cp[i * 3 + 2];
            lv[i] = lab[i];
        }
#pragma unroll
        for (int i = 0; i < CKK; ++i) {
            if (lv[i] != 1) {
                float mind = MINDIS_INITF;
#pragma unroll
                for (int j = 0; j < CKK; ++j) {
                    if (lv[j] == 1) {
                        float dx = x[i] - x[j], dy = y[i] - y[j], dz = z[i] - z[j];
                        float d2 = dx * dx + dy * dy + dz * dz;
                        mind = fminf(mind, d2);
                    }
                }
                convexSum += mind;
            }
        }
    }

    // block reduce both sums
#pragma unroll
    for (int o = 32; o > 0; o >>= 1) {
        skelSum += __shfl_down(skelSum, o, 64);
        convexSum += __shfl_down(convexSum, o, 64);
    }
    __shared__ float s_a[4], s_b[4];
    const int wave = tid >> 6, lane = tid & 63;
    if (lane == 0) { s_a[wave] = skelSum; s_b[wave] = convexSum; }
    __syncthreads();
    if (tid == 0) {
        float sSum = s_a[0] + s_a[1] + s_a[2] + s_a[3];
        float cSum = s_b[0] + s_b[1] + s_b[2] + s_b[3];
        float loss_convex = cSum / (float)(BATCH * NCLS);
        float loss_cd = (sumN[0] + sSum) / (float)BATCH;
        out[0] = 1.0f * loss_convex + 0.1f * loss_cd;
    }
}

extern "C" void kernel_launch(void* const* d_in, const int* in_sizes, int n_in,
                              void* d_out, int out_size, void* d_ws, size_t ws_size,
                              hipStream_t stream) {
    const float* xyz = (const float*)d_in[0];
    const float* skel = (const float*)d_in[1];
    // d_in[2] = weights (unused by reference)
    const int* labels = (const int*)d_in[3];
    // d_in[4] = num_class scalar (compile-time constant 100)
    float* out = (float*)d_out;

    unsigned int* minbits = (unsigned int*)d_ws;
    float* sumN = (float*)d_ws + BATCH * MSKEL;

    k_init<<<(BATCH * MSKEL + 256) / 256, 256, 0, stream>>>(minbits, sumN);
    k_nside<<<BATCH * (NPTS / 256), 256, 0, stream>>>(xyz, skel, sumN);
    k_mside<<<BATCH * (NPTS / TILE_N), 256, 0, stream>>>(xyz, skel, minbits);
    k_final<<<1, 256, 0, stream>>>(skel, labels, minbits, sumN, out);
}

// Round 2
// 143.157 us; speedup vs baseline: 1.4360x; 1.4360x over previous
//
#include <hip/hip_runtime.h>

#define BATCH 8
#define NPTS 16384
#define MSKEL 1000
#define NCLS 100
#define CKK 10
#define MINDIS_INITF 100000.0f

// ws layout: uint minbits[BATCH*MSKEL]  (8000 * 4B)
//            float partials[256]        (n-side per-block sums)

// n-side chamfer: 256 blocks (32/batch, 512 pts each), 2 pts/thread.
// skel staged in LDS as (-sx,-sy,-sz, 0.5*|s|^2); t = hs - p.s via 3 FMA;
// min d^2 = 2*min_t + |p|^2. Also fused: minbits init (blocks 0..31).
__global__ __launch_bounds__(256) void k_nside(const float* __restrict__ xyz,
                                               const float* __restrict__ skel,
                                               unsigned int* __restrict__ minbits,
                                               float* __restrict__ partials) {
    __shared__ float4 s_skel[MSKEL];
    const int bid = blockIdx.x;
    const int b = bid >> 5, tile = bid & 31;
    const int tid = threadIdx.x;

    // fused init: 32 blocks x 250 entries = 8000 (k_mside launches after us)
    if (bid < 32 && tid < 250) minbits[bid * 250 + tid] = 0x7F800000u;

    const float* sb = skel + (size_t)b * MSKEL * 3;
    for (int i = tid; i < MSKEL; i += 256) {
        float sx = sb[i * 3 + 0], sy = sb[i * 3 + 1], sz = sb[i * 3 + 2];
        s_skel[i] = make_float4(-sx, -sy, -sz, 0.5f * (sx * sx + sy * sy + sz * sz));
    }
    __syncthreads();

    const int n0 = tile * 512 + tid;
    const float* p0 = xyz + ((size_t)b * NPTS + n0) * 6;
    const float* p1 = p0 + 256 * 6;
    const float px0 = p0[0], py0 = p0[1], pz0 = p0[2];
    const float px1 = p1[0], py1 = p1[1], pz1 = p1[2];

    float mt0 = 3.4e38f, mt1 = 3.4e38f;
#pragma unroll 8
    for (int m = 0; m < MSKEL; ++m) {
        float4 s = s_skel[m];  // broadcast read: conflict-free
        float t0 = fmaf(px0, s.x, fmaf(py0, s.y, fmaf(pz0, s.z, s.w)));
        float t1 = fmaf(px1, s.x, fmaf(py1, s.y, fmaf(pz1, s.z, s.w)));
        mt0 = fminf(mt0, t0);
        mt1 = fminf(mt1, t1);
    }
    const float pp0 = px0 * px0 + py0 * py0 + pz0 * pz0;
    const float pp1 = px1 * px1 + py1 * py1 + pz1 * pz1;
    float d = sqrtf(fmaxf(fmaf(2.0f, mt0, pp0), 1e-12f)) +
              sqrtf(fmaxf(fmaf(2.0f, mt1, pp1), 1e-12f));

    // block reduce
#pragma unroll
    for (int o = 32; o > 0; o >>= 1) d += __shfl_down(d, o, 64);
    __shared__ float s_part[4];
    const int wave = tid >> 6, lane = tid & 63;
    if (lane == 0) s_part[wave] = d;
    __syncthreads();
    if (tid == 0) partials[bid] = s_part[0] + s_part[1] + s_part[2] + s_part[3];
}

// m-side chamfer: 256 blocks (32/batch, 512-pt tile), 4 skel pts/thread in regs.
// points staged as (x,y,z,|p|^2); u = |s|^2 - 2 p.s via 3 FMA; d^2 = u + |p|^2.
__global__ __launch_bounds__(256) void k_mside(const float* __restrict__ xyz,
                                               const float* __restrict__ skel,
                                               unsigned int* __restrict__ minbits) {
    __shared__ float4 s_pts[512];
    const int bid = blockIdx.x;
    const int b = bid >> 5, tile = bid & 31;
    const int tid = threadIdx.x;

    const float* xb = xyz + ((size_t)b * NPTS + tile * 512) * 6;
    for (int i = tid; i < 512; i += 256) {
        float x = xb[i * 6 + 0], y = xb[i * 6 + 1], z = xb[i * 6 + 2];
        s_pts[i] = make_float4(x, y, z, x * x + y * y + z * z);
    }
    __syncthreads();

    float m2x[4], m2y[4], m2z[4], ss[4], mind[4];
#pragma unroll
    for (int k = 0; k < 4; ++k) {
        int m = tid + k * 256;
        if (m < MSKEL) {
            const float* s = skel + ((size_t)b * MSKEL + m) * 3;
            float sx = s[0], sy = s[1], sz = s[2];
            m2x[k] = -2.0f * sx; m2y[k] = -2.0f * sy; m2z[k] = -2.0f * sz;
            ss[k] = sx * sx + sy * sy + sz * sz;
        } else {
            m2x[k] = 0.0f; m2y[k] = 0.0f; m2z[k] = 0.0f; ss[k] = 0.0f;
        }
        mind[k] = 3.4e38f;
    }

#pragma unroll 4
    for (int n = 0; n < 512; ++n) {
        float4 r = s_pts[n];  // broadcast read
#pragma unroll
        for (int k = 0; k < 4; ++k) {
            float u = fmaf(r.x, m2x[k], fmaf(r.y, m2y[k], fmaf(r.z, m2z[k], ss[k])));
            mind[k] = fminf(mind[k], u + r.w);
        }
    }
#pragma unroll
    for (int k = 0; k < 4; ++k) {
        int m = tid + k * 256;
        if (m < MSKEL) {
            // clamp fp-cancellation negatives to 0 so uint ordering == float ordering
            atomicMin(&minbits[b * MSKEL + m], __float_as_uint(fmaxf(mind[k], 0.0f)));
        }
    }
}

// finalize: sum n-side partials + m-side mins + convex-hull term
__global__ __launch_bounds__(256) void k_final(const float* __restrict__ skel,
                                               const int* __restrict__ labels,
                                               const unsigned int* __restrict__ minbits,
                                               const float* __restrict__ partials,
                                               float* __restrict__ out) {
    const int tid = threadIdx.x;
    float cd = partials[tid];  // 256 partials, one per thread
    for (int i = tid; i < BATCH * MSKEL; i += 256) {
        cd += sqrtf(fmaxf(__uint_as_float(minbits[i]), 1e-12f));
    }

    float convexSum = 0.0f;
    for (int task = tid; task < BATCH * NCLS; task += 256) {
        const int b = task / NCLS, c = task % NCLS;
        const float* cp = skel + ((size_t)b * MSKEL + c * CKK) * 3;
        const int* lab = labels + (size_t)b * NCLS * CKK + c * CKK;
        float x[CKK], y[CKK], z[CKK];
        int lv[CKK];
#pragma unroll
        for (int i = 0; i < CKK; ++i) {
            x[i] = cp[i * 3 + 0]; y[i] = cp[i * 3 + 1]; z[i] = cp[i * 3 + 2];
            lv[i] = lab[i];
        }
#pragma unroll
        for (int i = 0; i < CKK; ++i) {
            if (lv[i] != 1) {
                float mind = MINDIS_INITF;
#pragma unroll
                for (int j = 0; j < CKK; ++j) {
                    if (lv[j] == 1) {
                        float dx = x[i] - x[j], dy = y[i] - y[j], dz = z[i] - z[j];
                        mind = fminf(mind, dx * dx + dy * dy + dz * dz);
                    }
                }
                convexSum += mind;
            }
        }
    }

#pragma unroll
    for (int o = 32; o > 0; o >>= 1) {
        cd += __shfl_down(cd, o, 64);
        convexSum += __shfl_down(convexSum, o, 64);
    }
    __shared__ float s_a[4], s_b[4];
    const int wave = tid >> 6, lane = tid & 63;
    if (lane == 0) { s_a[wave] = cd; s_b[wave] = convexSum; }
    __syncthreads();
    if (tid == 0) {
        float cdSum = s_a[0] + s_a[1] + s_a[2] + s_a[3];
        float cxSum = s_b[0] + s_b[1] + s_b[2] + s_b[3];
        out[0] = cxSum / (float)(BATCH * NCLS) + 0.1f * (cdSum / (float)BATCH);
    }
}

extern "C" void kernel_launch(void* const* d_in, const int* in_sizes, int n_in,
                              void* d_out, int out_size, void* d_ws, size_t ws_size,
                              hipStream_t stream) {
    const float* xyz = (const float*)d_in[0];
    const float* skel = (const float*)d_in[1];
    // d_in[2] = weights (unused by reference)
    const int* labels = (const int*)d_in[3];
    float* out = (float*)d_out;

    unsigned int* minbits = (unsigned int*)d_ws;
    float* partials = (float*)d_ws + BATCH * MSKEL;

    k_nside<<<BATCH * 32, 256, 0, stream>>>(xyz, skel, minbits, partials);
    k_mside<<<BATCH * 32, 256, 0, stream>>>(xyz, skel, minbits);
    k_final<<<1, 256, 0, stream>>>(skel, labels, minbits, partials, out);
}

// Round 3
// 136.848 us; speedup vs baseline: 1.5022x; 1.0461x over previous
//
#include <hip/hip_runtime.h>

#define BATCH 8
#define NPTS 16384
#define MSKEL 1000
#define NCLS 100
#define CKK 10
#define MINDIS_INITF 100000.0f

// ws layout (floats):
//   [0 .. 8000*32)            tileMins[(b*1000+m)*32 + tile]  (m-side per-tile mins)
//   [256000 .. 256256)        partials[256]                   (n-side per-block sums)

// Fused chamfer: 512 blocks, 2/CU.
//   blocks [0,256):   n-side — b=bid>>5, 512-pt tile, 2 pts/thread, skel in LDS
//                     as (-sx,-sy,-sz,0.5|s|^2); min_m t = 0.5|s|^2 - p.s;
//                     d^2 = 2*min_t + |p|^2.  (4 VALU/pair)
//   blocks [256,512): m-side — 512-pt tile in LDS as (x,y,z,|p|^2), 4 skel
//                     pts/thread in regs; d^2 = fma-chain + |p|^2. (5 VALU/pair)
__global__ __launch_bounds__(256) void k_chamfer(const float* __restrict__ xyz,
                                                 const float* __restrict__ skel,
                                                 float* __restrict__ tileMins,
                                                 float* __restrict__ partials) {
    __shared__ float4 s_buf[MSKEL];  // nside: 1000 skel; mside: 512 pts
    const int bid = blockIdx.x;
    const int tid = threadIdx.x;

    if (bid < 256) {
        // ---------------- n-side ----------------
        const int b = bid >> 5, tile = bid & 31;
        const float* sb = skel + (size_t)b * MSKEL * 3;
        for (int i = tid; i < MSKEL; i += 256) {
            float sx = sb[i * 3 + 0], sy = sb[i * 3 + 1], sz = sb[i * 3 + 2];
            s_buf[i] = make_float4(-sx, -sy, -sz, 0.5f * (sx * sx + sy * sy + sz * sz));
        }
        __syncthreads();

        const int n0 = tile * 512 + tid;
        const float* p0 = xyz + ((size_t)b * NPTS + n0) * 6;
        const float* p1 = p0 + 256 * 6;
        const float px0 = p0[0], py0 = p0[1], pz0 = p0[2];
        const float px1 = p1[0], py1 = p1[1], pz1 = p1[2];

        float mt0 = 3.4e38f, mt1 = 3.4e38f;
#pragma unroll 8
        for (int m = 0; m < MSKEL; ++m) {
            float4 s = s_buf[m];  // broadcast read: conflict-free
            float t0 = fmaf(px0, s.x, fmaf(py0, s.y, fmaf(pz0, s.z, s.w)));
            float t1 = fmaf(px1, s.x, fmaf(py1, s.y, fmaf(pz1, s.z, s.w)));
            mt0 = fminf(mt0, t0);
            mt1 = fminf(mt1, t1);
        }
        const float pp0 = px0 * px0 + py0 * py0 + pz0 * pz0;
        const float pp1 = px1 * px1 + py1 * py1 + pz1 * pz1;
        float d = sqrtf(fmaxf(fmaf(2.0f, mt0, pp0), 1e-12f)) +
                  sqrtf(fmaxf(fmaf(2.0f, mt1, pp1), 1e-12f));

#pragma unroll
        for (int o = 32; o > 0; o >>= 1) d += __shfl_down(d, o, 64);
        __shared__ float s_part[4];
        const int wave = tid >> 6, lane = tid & 63;
        if (lane == 0) s_part[wave] = d;
        __syncthreads();
        if (tid == 0) partials[bid] = s_part[0] + s_part[1] + s_part[2] + s_part[3];
    } else {
        // ---------------- m-side ----------------
        const int id = bid - 256;
        const int b = id >> 5, tile = id & 31;
        const float* xb = xyz + ((size_t)b * NPTS + tile * 512) * 6;
        for (int i = tid; i < 512; i += 256) {
            float x = xb[i * 6 + 0], y = xb[i * 6 + 1], z = xb[i * 6 + 2];
            s_buf[i] = make_float4(x, y, z, x * x + y * y + z * z);
        }
        __syncthreads();

        float m2x[4], m2y[4], m2z[4], ss[4], mind[4];
#pragma unroll
        for (int k = 0; k < 4; ++k) {
            int m = tid + k * 256;
            if (m < MSKEL) {
                const float* s = skel + ((size_t)b * MSKEL + m) * 3;
                float sx = s[0], sy = s[1], sz = s[2];
                m2x[k] = -2.0f * sx; m2y[k] = -2.0f * sy; m2z[k] = -2.0f * sz;
                ss[k] = sx * sx + sy * sy + sz * sz;
            } else {
                m2x[k] = 0.0f; m2y[k] = 0.0f; m2z[k] = 0.0f; ss[k] = 0.0f;
            }
            mind[k] = 3.4e38f;
        }

#pragma unroll 4
        for (int n = 0; n < 512; ++n) {
            float4 r = s_buf[n];  // broadcast read
#pragma unroll
            for (int k = 0; k < 4; ++k) {
                float u = fmaf(r.x, m2x[k], fmaf(r.y, m2y[k], fmaf(r.z, m2z[k], ss[k])));
                mind[k] = fminf(mind[k], u + r.w);
            }
        }
#pragma unroll
        for (int k = 0; k < 4; ++k) {
            int m = tid + k * 256;
            if (m < MSKEL) tileMins[((size_t)(b * MSKEL + m)) * 32 + tile] = mind[k];
        }
    }
}

// finalize: reduce m-side tile mins (32 contiguous floats per entry), n-side
// partials, convex-hull term; write the scalar.
__global__ __launch_bounds__(256) void k_final(const float* __restrict__ skel,
                                               const int* __restrict__ labels,
                                               const float* __restrict__ tileMins,
                                               const float* __restrict__ partials,
                                               float* __restrict__ out) {
    const int tid = threadIdx.x;
    float cd = partials[tid];  // exactly 256 partials
    for (int i = tid; i < BATCH * MSKEL; i += 256) {
        const float4* tp = (const float4*)(tileMins + (size_t)i * 32);
        float4 m0 = tp[0];
#pragma unroll
        for (int j = 1; j < 8; ++j) {
            float4 v = tp[j];
            m0.x = fminf(m0.x, v.x); m0.y = fminf(m0.y, v.y);
            m0.z = fminf(m0.z, v.z); m0.w = fminf(m0.w, v.w);
        }
        float mn = fminf(fminf(m0.x, m0.y), fminf(m0.z, m0.w));
        cd += sqrtf(fmaxf(mn, 1e-12f));
    }

    float convexSum = 0.0f;
    for (int task = tid; task < BATCH * NCLS; task += 256) {
        const int b = task / NCLS, c = task % NCLS;
        const float* cp = skel + ((size_t)b * MSKEL + c * CKK) * 3;
        const int* lab = labels + (size_t)b * NCLS * CKK + c * CKK;
        float x[CKK], y[CKK], z[CKK];
        int lv[CKK];
#pragma unroll
        for (int i = 0; i < CKK; ++i) {
            x[i] = cp[i * 3 + 0]; y[i] = cp[i * 3 + 1]; z[i] = cp[i * 3 + 2];
            lv[i] = lab[i];
        }
#pragma unroll
        for (int i = 0; i < CKK; ++i) {
            if (lv[i] != 1) {
                float mind = MINDIS_INITF;
#pragma unroll
                for (int j = 0; j < CKK; ++j) {
                    if (lv[j] == 1) {
                        float dx = x[i] - x[j], dy = y[i] - y[j], dz = z[i] - z[j];
                        mind = fminf(mind, dx * dx + dy * dy + dz * dz);
                    }
                }
                convexSum += mind;
            }
        }
    }

#pragma unroll
    for (int o = 32; o > 0; o >>= 1) {
        cd += __shfl_down(cd, o, 64);
        convexSum += __shfl_down(convexSum, o, 64);
    }
    __shared__ float s_a[4], s_b[4];
    const int wave = tid >> 6, lane = tid & 63;
    if (lane == 0) { s_a[wave] = cd; s_b[wave] = convexSum; }
    __syncthreads();
    if (tid == 0) {
        float cdSum = s_a[0] + s_a[1] + s_a[2] + s_a[3];
        float cxSum = s_b[0] + s_b[1] + s_b[2] + s_b[3];
        out[0] = cxSum / (float)(BATCH * NCLS) + 0.1f * (cdSum / (float)BATCH);
    }
}

extern "C" void kernel_launch(void* const* d_in, const int* in_sizes, int n_in,
                              void* d_out, int out_size, void* d_ws, size_t ws_size,
                              hipStream_t stream) {
    const float* xyz = (const float*)d_in[0];
    const float* skel = (const float*)d_in[1];
    // d_in[2] = weights (unused by reference)
    const int* labels = (const int*)d_in[3];
    float* out = (float*)d_out;

    float* tileMins = (float*)d_ws;                       // 8000*32 floats
    float* partials = (float*)d_ws + BATCH * MSKEL * 32;  // 256 floats

    k_chamfer<<<512, 256, 0, stream>>>(xyz, skel, tileMins, partials);
    k_final<<<1, 256, 0, stream>>>(skel, labels, tileMins, partials, out);
}

// Round 4
// 106.110 us; speedup vs baseline: 1.9374x; 1.2897x over previous
//
#include <hip/hip_runtime.h>

#define BATCH 8
#define NPTS 16384
#define MSKEL 1000
#define NCLS 100
#define CKK 10
#define MINDIS_INITF 100000.0f

// ws float layout (all 16B-aligned):
//   skelN   : [0, 32000)            float4 (-sx,-sy,-sz, 0.5|s|^2) per (b,m)
//   ptsM    : [32000, 556288)       float4 (x,y,z,|p|^2)           per (b,n)
//   tileMins: [556288, 812288)      [ (b*32+tile)*1000 + m ]
//   partials: [812288, 812544)      n-side per-block sums (256)
#define OFF_PTSM 32000
#define OFF_TMIN (32000 + 524288)
#define OFF_PART (32000 + 524288 + 256000)

// prep: build skelN and ptsM; zero the output accumulator.
__global__ __launch_bounds__(256) void k_prep(const float* __restrict__ xyz,
                                              const float* __restrict__ skel,
                                              float4* __restrict__ skelN,
                                              float4* __restrict__ ptsM,
                                              float* __restrict__ out) {
    const int gid = blockIdx.x * 256 + threadIdx.x;  // 131072 threads exactly
    {
        const float* p = xyz + (size_t)gid * 6;
        float x = p[0], y = p[1], z = p[2];
        ptsM[gid] = make_float4(x, y, z, x * x + y * y + z * z);
    }
    if (gid < BATCH * MSKEL) {
        const float* s = skel + (size_t)gid * 3;
        float sx = s[0], sy = s[1], sz = s[2];
        skelN[gid] = make_float4(-sx, -sy, -sz, 0.5f * (sx * sx + sy * sy + sz * sz));
    }
    if (gid == 0) out[0] = 0.0f;
}

// Fused chamfer, 512 blocks (2/CU, 8 waves/CU). No LDS in hot loops:
// the wave-uniform operand streams through scalar loads (uniform index).
//   blocks [0,256):   n-side — 512-pt tile, 2 pts/thread in VGPRs, skel uniform.
//                     min_m t = 0.5|s|^2 - p.s; d^2 = 2*min_t + |p|^2.
//   blocks [256,512): m-side — 4 skel pts/thread in VGPRs, 512-pt tile uniform.
//                     d^2 = (|s|^2 - 2 p.s) + |p|^2.
__global__ __launch_bounds__(256) void k_chamfer(const float4* __restrict__ skelN,
                                                 const float4* __restrict__ ptsM,
                                                 float* __restrict__ tileMins,
                                                 float* __restrict__ partials) {
    const int bid = blockIdx.x;
    const int tid = threadIdx.x;

    if (bid < 256) {
        // ---------------- n-side ----------------
        const int b = bid >> 5, tile = bid & 31;
        const float4 r0 = ptsM[b * NPTS + tile * 512 + tid];
        const float4 r1 = ptsM[b * NPTS + tile * 512 + 256 + tid];
        const float4* __restrict__ sk = skelN + b * MSKEL;

        float mt0 = 3.4e38f, mt1 = 3.4e38f;
#pragma unroll 8
        for (int m = 0; m < MSKEL; ++m) {
            float4 s = sk[m];  // uniform index -> s_load_dwordx4 (scalar pipe)
            float t0 = fmaf(r0.x, s.x, fmaf(r0.y, s.y, fmaf(r0.z, s.z, s.w)));
            float t1 = fmaf(r1.x, s.x, fmaf(r1.y, s.y, fmaf(r1.z, s.z, s.w)));
            mt0 = fminf(mt0, t0);
            mt1 = fminf(mt1, t1);
        }
        float d = sqrtf(fmaxf(fmaf(2.0f, mt0, r0.w), 1e-12f)) +
                  sqrtf(fmaxf(fmaf(2.0f, mt1, r1.w), 1e-12f));

#pragma unroll
        for (int o = 32; o > 0; o >>= 1) d += __shfl_down(d, o, 64);
        __shared__ float s_part[4];
        const int wave = tid >> 6, lane = tid & 63;
        if (lane == 0) s_part[wave] = d;
        __syncthreads();
        if (tid == 0) partials[bid] = s_part[0] + s_part[1] + s_part[2] + s_part[3];
    } else {
        // ---------------- m-side ----------------
        const int id = bid - 256;
        const int b = id >> 5, tile = id & 31;

        float m2x[4], m2y[4], m2z[4], ss[4], mind[4];
#pragma unroll
        for (int k = 0; k < 4; ++k) {
            const int m = tid + k * 256;
            if (m < MSKEL) {
                float4 s = skelN[b * MSKEL + m];  // per-lane coalesced load
                m2x[k] = 2.0f * s.x;  // = -2*sx
                m2y[k] = 2.0f * s.y;
                m2z[k] = 2.0f * s.z;
                ss[k] = 2.0f * s.w;   // = |s|^2
            } else {
                m2x[k] = 0.0f; m2y[k] = 0.0f; m2z[k] = 0.0f; ss[k] = 0.0f;
            }
            mind[k] = 3.4e38f;
        }

        const float4* __restrict__ pp = ptsM + b * NPTS + tile * 512;
#pragma unroll 8
        for (int n = 0; n < 512; ++n) {
            float4 r = pp[n];  // uniform index -> s_load_dwordx4
#pragma unroll
            for (int k = 0; k < 4; ++k) {
                float u = fmaf(r.x, m2x[k], fmaf(r.y, m2y[k], fmaf(r.z, m2z[k], ss[k])));
                mind[k] = fminf(mind[k], u + r.w);
            }
        }
        float* tm = tileMins + (size_t)(b * 32 + tile) * MSKEL;
#pragma unroll
        for (int k = 0; k < 4; ++k) {
            const int m = tid + k * 256;
            if (m < MSKEL) tm[m] = mind[k];  // coalesced
        }
    }
}

// reduce: m-side 32-way min (coalesced across lanes) + n-side partials +
// convex-hull term; one atomicAdd per block into out[0] (pre-scaled).
__global__ __launch_bounds__(256) void k_reduce(const float* __restrict__ skel,
                                                const int* __restrict__ labels,
                                                const float* __restrict__ tileMins,
                                                const float* __restrict__ partials,
                                                float* __restrict__ out) {
    const int gid = blockIdx.x * 256 + threadIdx.x;  // 64 blocks = 16384 threads
    const int tid = threadIdx.x;
    float acc = 0.0f;

    if (gid < BATCH * MSKEL) {
        const int b = gid / MSKEL, m = gid - b * MSKEL;
        float mn = 3.4e38f;
#pragma unroll
        for (int t = 0; t < 32; ++t) {
            mn = fminf(mn, tileMins[(size_t)(b * 32 + t) * MSKEL + m]);  // coalesced
        }
        acc += 0.0125f * sqrtf(fmaxf(mn, 1e-12f));  // 0.1 / BATCH
    }
    if (gid < 256) acc += 0.0125f * partials[gid];

    if (gid < BATCH * NCLS) {
        const int b = gid / NCLS, c = gid - b * NCLS;
        const float* cp = skel + ((size_t)b * MSKEL + c * CKK) * 3;
        const int* lab = labels + (size_t)b * NCLS * CKK + c * CKK;
        float x[CKK], y[CKK], z[CKK];
        int lv[CKK];
#pragma unroll
        for (int i = 0; i < CKK; ++i) {
            x[i] = cp[i * 3 + 0]; y[i] = cp[i * 3 + 1]; z[i] = cp[i * 3 + 2];
            lv[i] = lab[i];
        }
        float convexSum = 0.0f;
#pragma unroll
        for (int i = 0; i < CKK; ++i) {
            if (lv[i] != 1) {
                float mind = MINDIS_INITF;
#pragma unroll
                for (int j = 0; j < CKK; ++j) {
                    if (lv[j] == 1) {
                        float dx = x[i] - x[j], dy = y[i] - y[j], dz = z[i] - z[j];
                        mind = fminf(mind, dx * dx + dy * dy + dz * dz);
                    }
                }
                convexSum += mind;
            }
        }
        acc += convexSum * (1.0f / (BATCH * NCLS));
    }

#pragma unroll
    for (int o = 32; o > 0; o >>= 1) acc += __shfl_down(acc, o, 64);
    __shared__ float s_part[4];
    const int wave = tid >> 6, lane = tid & 63;
    if (lane == 0) s_part[wave] = acc;
    __syncthreads();
    if (tid == 0) {
        atomicAdd(out, s_part[0] + s_part[1] + s_part[2] + s_part[3]);
    }
}

extern "C" void kernel_launch(void* const* d_in, const int* in_sizes, int n_in,
                              void* d_out, int out_size, void* d_ws, size_t ws_size,
                              hipStream_t stream) {
    const float* xyz = (const float*)d_in[0];
    const float* skel = (const float*)d_in[1];
    // d_in[2] = weights (unused by reference)
    const int* labels = (const int*)d_in[3];
    float* out = (float*)d_out;

    float4* skelN = (float4*)d_ws;
    float4* ptsM = (float4*)((float*)d_ws + OFF_PTSM);
    float* tileMins = (float*)d_ws + OFF_TMIN;
    float* partials = (float*)d_ws + OFF_PART;

    k_prep<<<512, 256, 0, stream>>>(xyz, skel, skelN, ptsM, out);
    k_chamfer<<<512, 256, 0, stream>>>(skelN, ptsM, tileMins, partials);
    k_reduce<<<64, 256, 0, stream>>>(skel, labels, tileMins, partials, out);
}